// Round 4
// baseline (7970.440 us; speedup 1.0000x reference)
//
#include <hip/hip_runtime.h>
#include <math.h>

#define BLOCK 256
#define PB 128  // pairs (problems) per block

// prep: W0 [27][128] -> W0p [32][128] (zero rows); W4 [128][25] -> W4p [128][32]
// (zero cols); b4 [25] -> b4p [32]
__global__ void prep_kernel(const float* __restrict__ W0, const float* __restrict__ W4,
                            const float* __restrict__ b4, float* __restrict__ W0p,
                            float* __restrict__ W4p, float* __restrict__ b4p) {
    const int t = blockIdx.x * blockDim.x + threadIdx.x;
    if (t < 32 * 128) {
        const int k = t >> 7, j = t & 127;
        W0p[t] = (k < 27) ? W0[k * 128 + j] : 0.0f;
    }
    if (t < 128 * 32) {
        const int k = t >> 5, j = t & 31;
        W4p[t] = (j < 25) ? W4[k * 25 + j] : 0.0f;
    }
    if (t < 32) b4p[t] = (t < 25) ? b4[t] : 0.0f;
}

// 16-output GEMM slice over NROWS input rows, double-buffered 4-row batches.
// W points at (row0, my 16 cols); row stride WSTRIDE. h read from hP[r*PB].
template <int NROWS, int WSTRIDE>
__device__ __forceinline__ void gemm16(const float* __restrict__ W,
                                       const float* __restrict__ hP,
                                       float* __restrict__ oc) {
    constexpr int NB = NROWS / 4;
    static_assert(NROWS % 8 == 0, "NB must be even");
    float4 Abuf[16], Bbuf[16];
    float hA[4], hB[4];
    // prologue: batch 0 -> A
#pragma unroll
    for (int r = 0; r < 4; ++r) {
#pragma unroll
        for (int q = 0; q < 4; ++q)
            Abuf[r * 4 + q] = *(const float4*)(W + r * WSTRIDE + q * 4);
        hA[r] = hP[r * PB];
    }
    for (int b = 0; b < NB; b += 2) {
        // issue batch b+1 -> B (NB even, b even => b+1 <= NB-1 always valid)
        {
            const float* Wb = W + (b + 1) * 4 * WSTRIDE;
            const float* hPb = hP + (b + 1) * 4 * PB;
#pragma unroll
            for (int r = 0; r < 4; ++r) {
#pragma unroll
                for (int q = 0; q < 4; ++q)
                    Bbuf[r * 4 + q] = *(const float4*)(Wb + r * WSTRIDE + q * 4);
                hB[r] = hPb[r * PB];
            }
        }
        // FMA batch A (rows b*4 .. b*4+3)
#pragma unroll
        for (int r = 0; r < 4; ++r) {
            const float h = hA[r];
#pragma unroll
            for (int q = 0; q < 4; ++q) {
                const float4 w = Abuf[r * 4 + q];
                oc[q * 4 + 0] = fmaf(h, w.x, oc[q * 4 + 0]);
                oc[q * 4 + 1] = fmaf(h, w.y, oc[q * 4 + 1]);
                oc[q * 4 + 2] = fmaf(h, w.z, oc[q * 4 + 2]);
                oc[q * 4 + 3] = fmaf(h, w.w, oc[q * 4 + 3]);
            }
        }
        // issue batch b+2 -> A (clamped redundant reload on the last iteration)
        {
            const int bn = (b + 2 < NB) ? (b + 2) : (NB - 2);
            const float* Wa = W + bn * 4 * WSTRIDE;
            const float* hPa = hP + bn * 4 * PB;
#pragma unroll
            for (int r = 0; r < 4; ++r) {
#pragma unroll
                for (int q = 0; q < 4; ++q)
                    Abuf[r * 4 + q] = *(const float4*)(Wa + r * WSTRIDE + q * 4);
                hA[r] = hPa[r * PB];
            }
        }
        // FMA batch B
#pragma unroll
        for (int r = 0; r < 4; ++r) {
            const float h = hB[r];
#pragma unroll
            for (int q = 0; q < 4; ++q) {
                const float4 w = Bbuf[r * 4 + q];
                oc[q * 4 + 0] = fmaf(h, w.x, oc[q * 4 + 0]);
                oc[q * 4 + 1] = fmaf(h, w.y, oc[q * 4 + 1]);
                oc[q * 4 + 2] = fmaf(h, w.z, oc[q * 4 + 2]);
                oc[q * 4 + 3] = fmaf(h, w.w, oc[q * 4 + 3]);
            }
        }
    }
}

// full 64-output layer for my half: 4 jq chunks of 16
template <int NROWS, int WSTRIDE>
__device__ __forceinline__ void layer64(const float* __restrict__ W,
                                        const float* __restrict__ bia,
                                        const float* __restrict__ hP,
                                        const int soff,  // s*64
                                        float* __restrict__ o) {
#pragma unroll
    for (int jq = 0; jq < 4; ++jq) {
        float* __restrict__ oc = o + jq * 16;
        const float* bp = bia + soff + jq * 16;
        const float4 bb0 = *(const float4*)(bp + 0);
        const float4 bb1 = *(const float4*)(bp + 4);
        const float4 bb2 = *(const float4*)(bp + 8);
        const float4 bb3 = *(const float4*)(bp + 12);
        oc[0] = bb0.x; oc[1] = bb0.y; oc[2] = bb0.z; oc[3] = bb0.w;
        oc[4] = bb1.x; oc[5] = bb1.y; oc[6] = bb1.z; oc[7] = bb1.w;
        oc[8] = bb2.x; oc[9] = bb2.y; oc[10] = bb2.z; oc[11] = bb2.w;
        oc[12] = bb3.x; oc[13] = bb3.y; oc[14] = bb3.z; oc[15] = bb3.w;
        gemm16<NROWS, WSTRIDE>(W + soff + jq * 16, hP, oc);
    }
}

__global__ __launch_bounds__(BLOCK, 2) void snarf_kernel(
    const float* __restrict__ xin, const float* __restrict__ bone_pts,
    const float* __restrict__ transforms, const float* __restrict__ delta_tf,
    const float* __restrict__ W0p, const float* __restrict__ b0,
    const float* __restrict__ W1, const float* __restrict__ b1,
    const float* __restrict__ W2, const float* __restrict__ b2,
    const float* __restrict__ W3, const float* __restrict__ b3,
    const float* __restrict__ W4p, const float* __restrict__ b4p,
    float* __restrict__ out, int Npts) {
    __shared__ float hL[128 * PB];  // 64 KiB, h[k][pair]
    const int tid = threadIdx.x;
    const int lane = tid & 63;
    const int s = (lane >> 5) & 1;          // my half of the pair
    const int pair = (tid >> 6) * 32 + (lane & 31);  // 0..127
    const int M = Npts * 6;
    const int m = blockIdx.x * PB + pair;
    if (m >= M) return;
    const int n = m / 6;
    const int i = m - n * 6;

    float* __restrict__ hP = &hL[pair];
    float* __restrict__ hS = hP + s * 64 * PB;  // my h-write region (rows s*64..)
    const int soff = s * 64;

    // zero h rows 27..31 once (layer0 reads 32 rows; rows 27..31 are W0p zero rows)
    for (int r = 27 + s; r < 32; r += 2) hP[r * PB] = 0.0f;

    const float tx = xin[n * 3 + 0], ty = xin[n * 3 + 1], tz = xin[n * 3 + 2];

    // ---- init candidate: i<5 -> i-th nearest bone's delta transform; i==5 -> identity
    float xk0, xk1, xk2;
    if (i < 5) {
        float dprev = -1.0f;
        int jprev = -1;
        for (int r = 0; r <= i; ++r) {
            float bd = 3.4028235e38f;
            int bj = 0;
            for (int j = 0; j < 24; ++j) {
                const float ax = tx - bone_pts[j * 3 + 0];
                const float ay = ty - bone_pts[j * 3 + 1];
                const float az = tz - bone_pts[j * 3 + 2];
                const float d = sqrtf(ax * ax + ay * ay + az * az);
                const bool taken = (d < dprev) || (d == dprev && j <= jprev);
                if (!taken && d < bd) { bd = d; bj = j; }
            }
            dprev = bd;
            jprev = bj;
        }
        const float* T = delta_tf + jprev * 16;
        xk0 = fmaf(T[0], tx, fmaf(T[1], ty, fmaf(T[2], tz, T[3])));
        xk1 = fmaf(T[4], tx, fmaf(T[5], ty, fmaf(T[6], tz, T[7])));
        xk2 = fmaf(T[8], tx, fmaf(T[9], ty, fmaf(T[10], tz, T[11])));
    } else {
        xk0 = tx; xk1 = ty; xk2 = tz;
    }

    // ---- Broyden state (duplicated per pair lane; bitwise identical)
    float gx0 = 0.f, gx1 = 0.f, gx2 = 0.f;
    float J00 = 1.f, J01 = 0.f, J02 = 0.f;
    float J10 = 0.f, J11 = 1.f, J12 = 0.f;
    float J20 = 0.f, J21 = 0.f, J22 = 1.f;
    float up0 = 0.f, up1 = 0.f, up2 = 0.f;
    float xo0 = xk0, xo1 = xk1, xo2 = xk2;
    float nopt = 0.f;
    float dx0 = 0.f, dx1 = 0.f, dx2 = 0.f;
    float dg0 = 0.f, dg1 = 0.f, dg2 = 0.f;
    bool mask = true;

    float o[64];

    int step = -1;  // -1 init eval, 0..7 Broyden, 8 final eval
    while (step <= 8) {
        bool m3 = mask;
        if (step >= 0 && step < 8) {
            if (__ballot(mask) == 0ull) { step = 8; continue; }
            if (m3) {
                dx0 = up0; dx1 = up1; dx2 = up2;
                xk0 += dx0; xk1 += dx1; xk2 += dx2;
            }
        }
        float cx0 = xk0, cx1 = xk1, cx2 = xk2;
        if (step == 8) { cx0 = xo0; cx1 = xo1; cx2 = xo2; }

        // ---- positional encoding (both lanes compute all 27; each writes its half)
        float pe[27];
        pe[0] = cx0; pe[1] = cx1; pe[2] = cx2;
#pragma unroll
        for (int sc = 0; sc < 4; ++sc) {
            const float f = (float)(1 << sc);
            float s0, c0, s1, c1, s2, c2;
            sincosf(f * cx0, &s0, &c0);
            sincosf(f * cx1, &s1, &c1);
            sincosf(f * cx2, &s2, &c2);
            pe[3 + sc * 3 + 0] = s0;
            pe[3 + sc * 3 + 1] = s1;
            pe[3 + sc * 3 + 2] = s2;
            pe[15 + sc * 3 + 0] = c0;
            pe[15 + sc * 3 + 1] = c1;
            pe[15 + sc * 3 + 2] = c2;
        }
        if (s == 0) {
#pragma unroll
            for (int j = 0; j < 14; ++j) hP[j * PB] = pe[j];
        } else {
#pragma unroll
            for (int j = 14; j < 27; ++j) hP[j * PB] = pe[j];
        }

        layer64<32, 128>(W0p, b0, hP, soff, o);
#pragma unroll
        for (int k = 0; k < 64; ++k) hS[k * PB] = fmaxf(o[k], 0.0f);
        layer64<128, 128>(W1, b1, hP, soff, o);
#pragma unroll
        for (int k = 0; k < 64; ++k) hS[k * PB] = fmaxf(o[k], 0.0f);
        layer64<128, 128>(W2, b2, hP, soff, o);
#pragma unroll
        for (int k = 0; k < 64; ++k) hS[k * PB] = fmaxf(o[k], 0.0f);
        layer64<128, 128>(W3, b3, hP, soff, o);
#pragma unroll
        for (int k = 0; k < 64; ++k) hS[k * PB] = fmaxf(o[k], 0.0f);

        // ---- output layer: my 16 of 32 padded logits
        float lg[16];
        {
            const float* bp = b4p + s * 16;
            const float4 bb0 = *(const float4*)(bp + 0);
            const float4 bb1 = *(const float4*)(bp + 4);
            const float4 bb2 = *(const float4*)(bp + 8);
            const float4 bb3 = *(const float4*)(bp + 12);
            lg[0] = bb0.x; lg[1] = bb0.y; lg[2] = bb0.z; lg[3] = bb0.w;
            lg[4] = bb1.x; lg[5] = bb1.y; lg[6] = bb1.z; lg[7] = bb1.w;
            lg[8] = bb2.x; lg[9] = bb2.y; lg[10] = bb2.z; lg[11] = bb2.w;
            lg[12] = bb3.x; lg[13] = bb3.y; lg[14] = bb3.z; lg[15] = bb3.w;
        }
        gemm16<128, 32>(W4p + s * 16, hP, lg);

        // exchange logits through LDS rows 0..31 (h fully consumed)
        {
            float* hW = hP + s * 16 * PB;
#pragma unroll
            for (int j = 0; j < 16; ++j) hW[j * PB] = lg[j];
        }
        float l25[25];
#pragma unroll
        for (int j = 0; j < 25; ++j) l25[j] = hP[j * PB];

        // softmax(5 * logits) over 25 (duplicated, identical)
        float zm = -3.4028235e38f;
#pragma unroll
        for (int j = 0; j < 25; ++j) {
            l25[j] = 5.0f * l25[j];
            zm = fmaxf(zm, l25[j]);
        }
        float ssum = 0.f;
#pragma unroll
        for (int j = 0; j < 25; ++j) {
            l25[j] = expf(l25[j] - zm);
            ssum += l25[j];
        }
        const float inv = 1.0f / ssum;

        float tf[12];
#pragma unroll
        for (int r = 0; r < 12; ++r) tf[r] = 0.f;
#pragma unroll
        for (int j = 0; j < 24; ++j) {
            const float wj = l25[j] * inv;
            const float* T = transforms + j * 16;
#pragma unroll
            for (int r = 0; r < 12; ++r) tf[r] = fmaf(wj, T[r], tf[r]);
        }
        {
            const float wj = l25[24] * inv;  // identity transform
            tf[0] += wj; tf[5] += wj; tf[10] += wj;
        }
        const float r0 = fmaf(tf[0], cx0, fmaf(tf[1], cx1, fmaf(tf[2], cx2, tf[3])));
        const float r1 = fmaf(tf[4], cx0, fmaf(tf[5], cx1, fmaf(tf[6], cx2, tf[7])));
        const float r2 = fmaf(tf[8], cx0, fmaf(tf[9], cx1, fmaf(tf[10], cx2, tf[11])));

        if (step == 8) {
            if (s == 0) {
                out[(size_t)m * 3 + 0] = r0;
                out[(size_t)m * 3 + 1] = r1;
                out[(size_t)m * 3 + 2] = r2;
                float* xopt_out = out + (size_t)M * 3;
                xopt_out[(size_t)m * 3 + 0] = xo0;
                xopt_out[(size_t)m * 3 + 1] = xo1;
                xopt_out[(size_t)m * 3 + 2] = xo2;
                out[(size_t)M * 6 + m] = nopt;
                out[(size_t)M * 7 + m] = (nopt < 1e-5f) ? 1.0f : 0.0f;
            }
            break;
        }

        const float g0 = r0 - tx, g1 = r1 - ty, g2 = r2 - tz;

        if (step == -1) {
            gx0 = g0; gx1 = g1; gx2 = g2;
            const float gn = sqrtf(g0 * g0 + g1 * g1 + g2 * g2);
            nopt = gn;
            up0 = -g0; up1 = -g1; up2 = -g2;  // Jinv = I
        } else {
            if (m3) {
                dg0 = g0 - gx0; dg1 = g1 - gx1; dg2 = g2 - gx2;
                gx0 += dg0; gx1 += dg1; gx2 += dg2;
            }
            const float gn = sqrtf(gx0 * gx0 + gx1 * gx1 + gx2 * gx2);
            const bool better = gn < nopt;
            if (better) {
                nopt = gn;
                xo0 = xk0; xo1 = xk1; xo2 = xk2;
            }
            mask = (nopt > 1e-5f) && (gn < 1.0f);

            const float v0 = dx0 * J00 + dx1 * J10 + dx2 * J20;
            const float v1 = dx0 * J01 + dx1 * J11 + dx2 * J21;
            const float v2 = dx0 * J02 + dx1 * J12 + dx2 * J22;
            const float Jd0 = J00 * dg0 + J01 * dg1 + J02 * dg2;
            const float Jd1 = J10 * dg0 + J11 * dg1 + J12 * dg2;
            const float Jd2 = J20 * dg0 + J21 * dg1 + J22 * dg2;
            const float a0 = dx0 - Jd0, a1 = dx1 - Jd1, a2 = dx2 - Jd2;
            float bden = v0 * dg0 + v1 * dg1 + v2 * dg2;
            bden += (bden >= 0.f) ? 1e-6f : -1e-6f;
            if (mask) {
                const float q0 = a0 / bden, q1 = a1 / bden, q2 = a2 / bden;
                J00 = fmaf(q0, v0, J00); J01 = fmaf(q0, v1, J01); J02 = fmaf(q0, v2, J02);
                J10 = fmaf(q1, v0, J10); J11 = fmaf(q1, v1, J11); J12 = fmaf(q1, v2, J12);
                J20 = fmaf(q2, v0, J20); J21 = fmaf(q2, v1, J21); J22 = fmaf(q2, v2, J22);
            }
            if (m3) {
                up0 = -(J00 * gx0 + J01 * gx1 + J02 * gx2);
                up1 = -(J10 * gx0 + J11 * gx1 + J12 * gx2);
                up2 = -(J20 * gx0 + J21 * gx1 + J22 * gx2);
            }
        }
        ++step;
    }
}

extern "C" void kernel_launch(void* const* d_in, const int* in_sizes, int n_in,
                              void* d_out, int out_size, void* d_ws, size_t ws_size,
                              hipStream_t stream) {
    const float* x = (const float*)d_in[0];
    const float* bone_pts = (const float*)d_in[1];
    const float* transforms = (const float*)d_in[2];
    const float* delta_tf = (const float*)d_in[3];
    const float* W0 = (const float*)d_in[4];
    const float* b0 = (const float*)d_in[5];
    const float* W1 = (const float*)d_in[6];
    const float* b1 = (const float*)d_in[7];
    const float* W2 = (const float*)d_in[8];
    const float* b2 = (const float*)d_in[9];
    const float* W3 = (const float*)d_in[10];
    const float* b3 = (const float*)d_in[11];
    const float* W4 = (const float*)d_in[12];
    const float* b4 = (const float*)d_in[13];
    float* out = (float*)d_out;

    float* W0p = (float*)d_ws;          // 32*128
    float* W4p = W0p + 32 * 128;        // 128*32
    float* b4p = W4p + 128 * 32;        // 32

    prep_kernel<<<16, 256, 0, stream>>>(W0, W4, b4, W0p, W4p, b4p);

    const int Npts = in_sizes[0] / 3;
    const int M = Npts * 6;
    const int blocks = (M + PB - 1) / PB;
    snarf_kernel<<<blocks, BLOCK, 0, stream>>>(
        x, bone_pts, transforms, delta_tf, W0p, b0, W1, b1, W2, b2, W3, b3,
        W4p, b4p, out, Npts);
}